// Round 1
// baseline (722.087 us; speedup 1.0000x reference)
//
#include <hip/hip_runtime.h>
#include <hip/hip_bf16.h>
#include <math.h>

#define N_NODE 30000
#define N_TRI  200000
#define DIM    128
#define OUTD   768
#define BATCH  2048
#define NROWA  4096
#define EPAD   30208   // 118*256 = 236*128
#define PADN   208     // EPAD - N_NODE
#define NTILE_E 236    // 128-row tiles in Ep
#define NTILE_A 32     // 128-row tiles in Ap
#define NTILE_EJ 118   // 256-col tiles of E
#define NTILE_AI 8     // 256-row tiles per chunk (2048/256)
#define NBLK_SCAN 118  // ceil(30000/256)
#define TILE_ELEMS (128*OUTD)
#define KBLK_ELEMS (128*32)
#define GAMMA_C 3.0f
#define LAMB_C  30.0f
#define TAU_C   10.0f

typedef __attribute__((ext_vector_type(8)))  __bf16 bf16x8;
typedef __attribute__((ext_vector_type(4)))  __bf16 bf16x4;
typedef __attribute__((ext_vector_type(2)))  __bf16 bf16x2;
typedef __attribute__((ext_vector_type(8)))  _Float16 half8;
typedef __attribute__((ext_vector_type(4)))  float f32x4;

__device__ __forceinline__ float waveSum(float v){
#pragma unroll
  for (int m=1;m<64;m<<=1) v += __shfl_xor(v, m, 64);
  return v;
}
__device__ __forceinline__ float halfSum(float v){
#pragma unroll
  for (int m=1;m<32;m<<=1) v += __shfl_xor(v, m, 64);
  return v;
}

__device__ __forceinline__ void atomicMinF(float* a, float v){
  if (v >= 0.f) atomicMin((int*)a, __float_as_int(v));
  else          atomicMax((unsigned int*)a, __float_as_uint(v));
}

__device__ __forceinline__ void gl2lds16(const void* g, void* l){
  __builtin_amdgcn_global_load_lds(
      (const __attribute__((address_space(1))) char*)g,
      (__attribute__((address_space(3))) char*)l, 16, 0, 0);
}

__device__ __forceinline__ int swz_off(int r, int q){
  return r*32 + ((q ^ ((r>>1)&3))<<3);
}

// ---------------- fill ----------------
__global__ void k_fill(float* __restrict__ p, long n, float v){
  long i = (long)blockIdx.x*blockDim.x + threadIdx.x;
  long st = (long)gridDim.x*blockDim.x;
  for (; i<n; i+=st) p[i]=v;
}

// ---------------- CSR build ----------------
__global__ __launch_bounds__(256) void k_hist(const int* __restrict__ rows, int* __restrict__ cnt){
  int t = blockIdx.x*256 + threadIdx.x;
  if (t < N_TRI) atomicAdd(&cnt[rows[t]], 1);
}

__global__ __launch_bounds__(256) void k_scanA(
    const int* __restrict__ c0, const int* __restrict__ c1, const int* __restrict__ c2,
    int* __restrict__ r0, int* __restrict__ r1, int* __restrict__ r2,
    int* __restrict__ btot, int n){
  const int* cnt = blockIdx.y==0 ? c0 : (blockIdx.y==1 ? c1 : c2);
  int* rp        = blockIdx.y==0 ? r0 : (blockIdx.y==1 ? r1 : r2);
  __shared__ int buf[256];
  int i = blockIdx.x*256 + threadIdx.x;
  int v = (i<n) ? cnt[i] : 0;
  buf[threadIdx.x] = v;
  __syncthreads();
  for (int off=1; off<256; off<<=1){
    int t = (threadIdx.x>=off) ? buf[threadIdx.x-off] : 0;
    __syncthreads();
    buf[threadIdx.x] += t;
    __syncthreads();
  }
  if (i<n) rp[i] = buf[threadIdx.x] - v;
  if (threadIdx.x==255) btot[blockIdx.y*NBLK_SCAN + blockIdx.x] = buf[255];
}

__global__ __launch_bounds__(128) void k_scanB(int* __restrict__ btot,
    int* __restrict__ r0, int* __restrict__ r1, int* __restrict__ r2, int n){
  __shared__ int buf[128];
  int c = blockIdx.x;
  int v = (threadIdx.x < NBLK_SCAN) ? btot[c*NBLK_SCAN + threadIdx.x] : 0;
  buf[threadIdx.x] = v;
  __syncthreads();
  for (int off=1; off<128; off<<=1){
    int t = (threadIdx.x>=off) ? buf[threadIdx.x-off] : 0;
    __syncthreads();
    buf[threadIdx.x] += t;
    __syncthreads();
  }
  if (threadIdx.x < NBLK_SCAN) btot[c*NBLK_SCAN + threadIdx.x] = buf[threadIdx.x] - v;
  if (threadIdx.x == 127){
    int* rp = c==0 ? r0 : (c==1 ? r1 : r2);
    rp[n] = buf[127];
  }
}

__global__ __launch_bounds__(256) void k_scanC(
    int* __restrict__ r0, int* __restrict__ r1, int* __restrict__ r2,
    const int* __restrict__ btot, int n){
  int* rp = blockIdx.y==0 ? r0 : (blockIdx.y==1 ? r1 : r2);
  int i = blockIdx.x*256 + threadIdx.x;
  if (i<n) rp[i] += btot[blockIdx.y*NBLK_SCAN + blockIdx.x];
}

__global__ __launch_bounds__(256) void k_place(const int* __restrict__ rows, const int* __restrict__ vals,
                        const int* __restrict__ rowptr, int* __restrict__ cur, int* __restrict__ idx, int mode){
  int t = blockIdx.x*256 + threadIdx.x;
  if (t < N_TRI){
    int r = rows[t];
    int p = atomicAdd(&cur[r], 1);
    idx[rowptr[r] + p] = mode ? vals[t] : t;
  }
}

// ---------------- fused sparse means + tanh -> interleaved bf16 features ----------------
__global__ __launch_bounds__(256) void k_feat0(
    const int* __restrict__ rpE, const int* __restrict__ idxE,
    const int* __restrict__ rpR, const int* __restrict__ idxR,
    const float* __restrict__ ent_emb, const float* __restrict__ rel_emb,
    __bf16* __restrict__ outb){
  int wave = threadIdx.x>>6, lane = threadIdx.x&63;
  int i = blockIdx.x*4 + wave;
  if (i >= N_NODE) return;
  int bE = rpE[i], eE = rpE[i+1];
  int bR = rpR[i], eR = rpR[i+1];
  float2 aE = {0.f,0.f}, aR = {0.f,0.f};
  for (int k=bE; k<eE; ++k){
    int c = idxE[k];
    float2 v = *(const float2*)(ent_emb + (size_t)c*DIM + lane*2);
    aE.x += v.x; aE.y += v.y;
  }
  for (int k=bR; k<eR; ++k){
    int c = idxR[k];
    float2 v = *(const float2*)(rel_emb + (size_t)c*DIM + lane*2);
    aR.x += v.x; aR.y += v.y;
  }
  float ie = 1.f/fmaxf((float)(eE-bE), 1.f);
  float ir = 1.f/fmaxf((float)(eR-bR), 1.f);
  bf16x2 oE, oR;
  oE[0] = (__bf16)tanhf(aE.x*ie); oE[1] = (__bf16)tanhf(aE.y*ie);
  oR[0] = (__bf16)tanhf(aR.x*ir); oR[1] = (__bf16)tanhf(aR.y*ir);
  *(bf16x2*)(outb + (size_t)i*OUTD +   0 + lane*2) = oE;
  *(bf16x2*)(outb + (size_t)i*OUTD + 128 + lane*2) = oR;
}

// ---------------- tri_rel direct + norm(bf16) + att logits ----------------
__global__ __launch_bounds__(256) void k_trinorm(
    const int* __restrict__ ridx1, const float* __restrict__ rval,
    const float* __restrict__ rel_emb,
    __bf16* __restrict__ tri, const float* __restrict__ attnE,
    const float* __restrict__ attnR, float* __restrict__ att4){
  __shared__ float ak[4][DIM];
  int tid = threadIdx.x;
  for (int idx=tid; idx<4*DIM; idx+=256){
    int k = idx>>7, d = idx&127;
    ak[k][d] = (k<2) ? attnE[k*DIM + d] : attnR[(k-2)*DIM + d];
  }
  __syncthreads();
  int half = tid>>5, l31 = tid&31;
  int t = blockIdx.x*8 + half;
  if (t >= N_TRI) return;
  int rr = ridx1[t];
  float rv = rval[t];
  float4 v = *(const float4*)(rel_emb + (size_t)rr*DIM + l31*4);
  v.x *= rv; v.y *= rv; v.z *= rv; v.w *= rv;
  float ss = halfSum(v.x*v.x + v.y*v.y + v.z*v.z + v.w*v.w);
  float inv = 1.f/fmaxf(sqrtf(ss), 1e-12f);
  v.x *= inv; v.y *= inv; v.z *= inv; v.w *= inv;
  bf16x4 b; b[0]=(__bf16)v.x; b[1]=(__bf16)v.y; b[2]=(__bf16)v.z; b[3]=(__bf16)v.w;
  *(bf16x4*)(tri + (size_t)t*DIM + l31*4) = b;
#pragma unroll
  for (int k=0;k<4;k++){
    const float* a = &ak[k][l31*4];
    float p = halfSum(v.x*a[0] + v.y*a[1] + v.z*a[2] + v.w*a[3]);
    if (l31==0) att4[(size_t)k*N_TRI + t] = p;
  }
}

// ---------------- fused GAT layer ----------------
__global__ __launch_bounds__(256) void k_gat(
    const int* __restrict__ rowptr, const int* __restrict__ idx, const int* __restrict__ cols,
    const __bf16* __restrict__ tri,
    const float* __restrict__ attE, const float* __restrict__ attR,
    __bf16* __restrict__ outb, int inOff, int outOff){
  int wave = threadIdx.x>>6, lane = threadIdx.x&63;
  int i = blockIdx.x*4 + wave;
  if (i >= N_NODE) return;
  int l31 = lane&31;
  const float* att = (lane < 32) ? attE : attR;
  int beg = rowptr[i], end = rowptr[i+1];
  float a0=0.f, a1=0.f, a2=0.f, a3=0.f;
  if (end > beg){
    float z = 0.f;
    int t0 = idx[beg];
    int c0 = cols[t0];
    bf16x4 u4 = *(const bf16x4*)(tri + (size_t)t0*DIM + l31*4);
    bf16x4 f4 = *(const bf16x4*)(outb + (size_t)c0*OUTD + inOff + lane*4);
    float atv = att[t0];
    for (int k=beg; k<end; ++k){
      bf16x4 u4c = u4, f4c = f4;
      float atc = atv;
      if (k+1 < end){
        int t1 = idx[k+1];
        int c1 = cols[t1];
        u4 = *(const bf16x4*)(tri + (size_t)t1*DIM + l31*4);
        f4 = *(const bf16x4*)(outb + (size_t)c1*OUTD + inOff + lane*4);
        atv = att[t1];
      }
      float u0=(float)u4c[0], u1=(float)u4c[1], u2=(float)u4c[2], u3=(float)u4c[3];
      float f0=(float)f4c[0], f1=(float)f4c[1], f2=(float)f4c[2], f3=(float)f4c[3];
      float d = f0*u0 + f1*u1 + f2*u2 + f3*u3;
#pragma unroll
      for (int mm=1; mm<32; mm<<=1) d += __shfl_xor(d, mm, 64);
      float w = __expf(atc);
      z += w;
      float d2 = 2.f*d;
      a0 = fmaf(w, fmaf(-d2, u0, f0), a0);
      a1 = fmaf(w, fmaf(-d2, u1, f1), a1);
      a2 = fmaf(w, fmaf(-d2, u2, f2), a2);
      a3 = fmaf(w, fmaf(-d2, u3, f3), a3);
    }
    float iz = 1.f/z;
    a0 *= iz; a1 *= iz; a2 *= iz; a3 *= iz;
  }
  bf16x4 o;
  o[0] = (__bf16)tanhf(a0); o[1] = (__bf16)tanhf(a1);
  o[2] = (__bf16)tanhf(a2); o[3] = (__bf16)tanhf(a3);
  *(bf16x4*)(outb + (size_t)i*OUTD + outOff + lane*4) = o;
}

// ---------------- pack E ----------------
__global__ __launch_bounds__(256) void k_packE(const __bf16* __restrict__ outb, __bf16* __restrict__ Ep, float* __restrict__ esq){
  const int perm[6] = {0,2,4,1,3,5};
  int wave = threadIdx.x>>6, lane = threadIdx.x&63;
  int j = blockIdx.x*4 + wave;
  if (j >= EPAD) return;
  int jt = j>>7, r = j&127;
  __bf16* tb = Ep + (size_t)jt*TILE_ELEMS;
  float ss = 0.f;
  for (int c=lane; c<96; c+=64){
    int kb = c>>2, q = c&3;
    bf16x8 o;
    if (j < N_NODE){
      int ib = perm[c>>4], wb = c&15;
      o = *(const bf16x8*)(outb + (size_t)j*OUTD + ib*128 + wb*8);
#pragma unroll
      for (int e=0;e<8;e++){ float v = (float)o[e]; ss += v*v; }
    } else {
#pragma unroll
      for (int e=0;e<8;e++) o[e] = (__bf16)0.f;
    }
    *(bf16x8*)(tb + kb*KBLK_ELEMS + swz_off(r, q)) = o;
  }
  ss = waveSum(ss);
  if (lane==0) esq[j] = (j < N_NODE) ? ss : 0.f;
}

__global__ __launch_bounds__(256) void k_packA(const int* __restrict__ pairs, const __bf16* __restrict__ Ep,
    const __bf16* __restrict__ outb, const float* __restrict__ esq,
    __bf16* __restrict__ Ap, float* __restrict__ asq, float* __restrict__ pos){
  int wave = threadIdx.x>>6, lane = threadIdx.x&63;
  int p = blockIdx.x*4 + wave;
  if (p >= BATCH) return;
  int l = pairs[2*p], r = pairs[2*p+1];
  float ss = 0.f;
#pragma unroll
  for (int c=0;c<6;c++){
    int d = c*128 + lane*2;
    bf16x2 a = *(const bf16x2*)(outb + (size_t)l*OUTD + d);
    bf16x2 b = *(const bf16x2*)(outb + (size_t)r*OUTD + d);
    float dx = (float)a[0]-(float)b[0], dy = (float)a[1]-(float)b[1];
    ss += dx*dx + dy*dy;
  }
  ss = waveSum(ss);
  if (lane==0){ pos[p] = ss; asq[p] = esq[l]; asq[p+BATCH] = esq[r]; }
  int lt = l>>7, lr = l&127;
  int rt2 = r>>7, rr = r&127;
  int p0t = p>>7, p0r = p&127;
  int p1t = (p+BATCH)>>7, p1r = (p+BATCH)&127;
  for (int c=lane; c<96; c+=64){
    int kb = c>>2, q = c&3;
    bf16x8 vl = *(const bf16x8*)(Ep + (size_t)lt*TILE_ELEMS + kb*KBLK_ELEMS + swz_off(lr, q));
    *(bf16x8*)(Ap + (size_t)p0t*TILE_ELEMS + kb*KBLK_ELEMS + swz_off(p0r, q)) = vl;
    bf16x8 vr = *(const bf16x8*)(Ep + (size_t)rt2*TILE_ELEMS + kb*KBLK_ELEMS + swz_off(rr, q));
    *(bf16x8*)(Ap + (size_t)p1t*TILE_ELEMS + kb*KBLK_ELEMS + swz_off(p1r, q)) = vr;
  }
}

// ---------------- GEMM: 256x256 tile, 8 waves, 4-phase/K-tile counted-vmcnt pipeline ----------------
// LDS: 2 x { A: 4 chunks of 128x32 (32KB), B: same (32KB) } = 128KB + 12KB epilogue scratch.
// Phase schedule per K-tile t (buffers: cur=t&1, staging into the ring with 1-1.5 tile lead):
//   ph1: ds_read A[m0-3] + B[n0-1]; stage (t+1).A rt0 ; bar; MFMA q(0,0); bar
//   ph2: ds_read B[n2-3]          ; stage (t+1).A rt1 ; bar; MFMA q(0,1); bar
//   ph3: ds_read A[m4-7]          ; stage (t+2).B rt0 ; bar; MFMA q(1,0); bar
//   ph4:                            stage (t+2).B rt1 ;      MFMA q(1,1); vmcnt(4); bar
// WAR safety: B region of buf[t] last read ph2 (drained by ph2's 2nd barrier) -> staged ph3/4.
//             A region of buf[t-1] last read at (t-1).ph3 -> staged at t.ph1/2.
// RAW safety: vmcnt(4) at tile end leaves only the 2 newest half-tiles (next B pair) in flight.
__global__ __launch_bounds__(512,2) void k_gemm(
    const __bf16* __restrict__ Ap, const __bf16* __restrict__ Ep,
    const float* __restrict__ asq, const float* __restrict__ esq,
    const int* __restrict__ pairs,
    float* __restrict__ rs1, float* __restrict__ rs2, float* __restrict__ rmin,
    _Float16* __restrict__ neg16, int biOff)
{
  __shared__ __align__(16) char smem[143360];
  const int tid = threadIdx.x;
  const int w = tid>>6, lane = tid&63, quad = lane>>4, l16 = lane&15;
  const int wr = w>>2, wc = w&3;

  // XCD-aware swizzle (944 blocks, 944%8==0 -> bijective): same-XCD blocks share bj.
  int wg = blockIdx.x*NTILE_EJ + blockIdx.y;
  const int biL = wg & 7;
  const int bj  = wg >> 3;
  const int bi  = biOff + biL;

  const __bf16* Abase = Ap + (size_t)(bi*2)*TILE_ELEMS;
  const __bf16* Bbase = Ep + (size_t)(bj*2)*TILE_ELEMS;

  const int s0b = swz_off(l16, quad)*2;          // byte offset within a 128x32 chunk
  const int aBase = wr*16384 + s0b;              // + cur*65536 + ks*8192 + m*1024
  const int bBase = 32768 + (wc>>1)*16384 + (wc&1)*4096 + s0b;  // + cur*65536 + ks*8192 + n*1024

  const f32x4 zf = {0.f,0.f,0.f,0.f};
  f32x4 acc[8][4];
#pragma unroll
  for (int m=0;m<8;m++)
#pragma unroll
    for (int n=0;n<4;n++) acc[m][n] = zf;

  auto stageA = [&](int t, int rt){
    const __bf16* src = Abase + (size_t)rt*TILE_ELEMS + (size_t)(t*2)*KBLK_ELEMS + tid*8;
    char* dst = smem + (t&1)*65536 + rt*16384 + tid*16;
    gl2lds16(src, dst);
    gl2lds16(src + KBLK_ELEMS, dst + 8192);
  };
  auto stageB = [&](int t, int rt){
    const __bf16* src = Bbase + (size_t)rt*TILE_ELEMS + (size_t)(t*2)*KBLK_ELEMS + tid*8;
    char* dst = smem + (t&1)*65536 + 32768 + rt*16384 + tid*16;
    gl2lds16(src, dst);
    gl2lds16(src + KBLK_ELEMS, dst + 8192);
  };

  // prologue: tile0 fully + tile1 B-pair; oldest 8 loads = tile0
  stageB(0,0); stageB(0,1); stageA(0,0); stageA(0,1); stageB(1,0); stageB(1,1);
  asm volatile("s_waitcnt vmcnt(4)" ::: "memory");
  __builtin_amdgcn_s_barrier();

  bf16x8 aF[4][2], bF[2][2][2];

#pragma unroll 1
  for (int t=0; t<12; ++t){
    const char* bufc = smem + (t&1)*65536;

    // ---- phase 1 ----
#pragma unroll
    for (int m4=0;m4<4;m4++)
#pragma unroll
      for (int ks=0;ks<2;ks++)
        aF[m4][ks] = *(const bf16x8*)(bufc + aBase + ks*8192 + m4*1024);
#pragma unroll
    for (int n2=0;n2<2;n2++)
#pragma unroll
      for (int ks=0;ks<2;ks++)
        bF[0][n2][ks] = *(const bf16x8*)(bufc + bBase + ks*8192 + n2*1024);
    if (t+1<12) stageA(t+1, 0);
    __builtin_amdgcn_s_barrier();
    __builtin_amdgcn_s_setprio(1);
#pragma unroll
    for (int m4=0;m4<4;m4++)
#pragma unroll
      for (int n2=0;n2<2;n2++)
#pragma unroll
        for (int ks=0;ks<2;ks++)
          acc[m4][n2] = __builtin_amdgcn_mfma_f32_16x16x32_bf16(aF[m4][ks], bF[0][n2][ks], acc[m4][n2],0,0,0);
    __builtin_amdgcn_s_setprio(0);
    __builtin_amdgcn_s_barrier();

    // ---- phase 2 ----
#pragma unroll
    for (int n2=0;n2<2;n2++)
#pragma unroll
      for (int ks=0;ks<2;ks++)
        bF[1][n2][ks] = *(const bf16x8*)(bufc + bBase + ks*8192 + (2+n2)*1024);
    if (t+1<12) stageA(t+1, 1);
    __builtin_amdgcn_s_barrier();
    __builtin_amdgcn_s_setprio(1);
#pragma unroll
    for (int m4=0;m4<4;m4++)
#pragma unroll
      for (int n2=0;n2<2;n2++)
#pragma unroll
        for (int ks=0;ks<2;ks++)
          acc[m4][2+n2] = __builtin_amdgcn_mfma_f32_16x16x32_bf16(aF[m4][ks], bF[1][n2][ks], acc[m4][2+n2],0,0,0);
    __builtin_amdgcn_s_setprio(0);
    __builtin_amdgcn_s_barrier();

    // ---- phase 3 ----
#pragma unroll
    for (int m4=0;m4<4;m4++)
#pragma unroll
      for (int ks=0;ks<2;ks++)
        aF[m4][ks] = *(const bf16x8*)(bufc + aBase + ks*8192 + (4+m4)*1024);
    if (t+2<12) stageB(t+2, 0);
    __builtin_amdgcn_s_barrier();
    __builtin_amdgcn_s_setprio(1);
#pragma unroll
    for (int m4=0;m4<4;m4++)
#pragma unroll
      for (int n2=0;n2<2;n2++)
#pragma unroll
        for (int ks=0;ks<2;ks++)
          acc[4+m4][n2] = __builtin_amdgcn_mfma_f32_16x16x32_bf16(aF[m4][ks], bF[0][n2][ks], acc[4+m4][n2],0,0,0);
    __builtin_amdgcn_s_setprio(0);
    __builtin_amdgcn_s_barrier();

    // ---- phase 4 ----
    if (t+2<12) stageB(t+2, 1);
    __builtin_amdgcn_s_setprio(1);
#pragma unroll
    for (int m4=0;m4<4;m4++)
#pragma unroll
      for (int n2=0;n2<2;n2++)
#pragma unroll
        for (int ks=0;ks<2;ks++)
          acc[4+m4][2+n2] = __builtin_amdgcn_mfma_f32_16x16x32_bf16(aF[m4][ks], bF[1][n2][ks], acc[4+m4][2+n2],0,0,0);
    __builtin_amdgcn_s_setprio(0);
    if (t < 10) asm volatile("s_waitcnt vmcnt(4)" ::: "memory");
    else        asm volatile("s_waitcnt vmcnt(0)" ::: "memory");
    __builtin_amdgcn_s_barrier();
  }

  // ---- epilogue: neg16 store + quad-reduced moment partials in side scratch ----
  float* redS = (float*)(smem + 131072);   // [3][256][4] fp32 = 12KB
  int jcol[4]; bool val[4]; float esqv[4];
#pragma unroll
  for (int n=0;n<4;n++){
    jcol[n] = bj*256 + wc*64 + n*16 + l16;
    val[n] = jcol[n] < N_NODE;
    esqv[n] = esq[jcol[n]];
  }
  const int rowB = bi*256;
  size_t tBase = ((size_t)bj*8 + biL)*65536;
#pragma unroll
  for (int m=0;m<8;m++){
    _Float16 h16[16];
#pragma unroll
    for (int reg=0;reg<4;reg++){
      int il = wr*128 + m*16 + quad*4 + reg;
      int i = rowB + il;
      int p = i & (BATCH-1);
      int li = pairs[2*p], ri = pairs[2*p+1];
      float av = asq[i];
      float s=0.f, q=0.f, mn=1e30f;
#pragma unroll
      for (int n=0;n<4;n++){
        float neg = (av + esqv[n]) - 2.f*acc[m][n][reg];
        s += neg;
        q = fmaf(neg, neg, q);
        bool bad = (jcol[n]==li) | (jcol[n]==ri) | (!val[n]);
        mn = fminf(mn, bad ? 1e30f : neg);
        h16[reg*4+n] = (_Float16)neg;
      }
#pragma unroll
      for (int msk=1; msk<16; msk<<=1){
        s += __shfl_xor(s, msk, 64);
        q += __shfl_xor(q, msk, 64);
        mn = fminf(mn, __shfl_xor(mn, msk, 64));
      }
      if (l16==0){
        redS[       il*4 + wc] = s;
        redS[1024 + il*4 + wc] = q;
        redS[2048 + il*4 + wc] = mn;
      }
    }
    _Float16* dst = neg16 + tBase + ((size_t)(w*8 + m))*1024 + lane*16;
    *(half8*)(dst)     = *(half8*)&h16[0];
    *(half8*)(dst + 8) = *(half8*)&h16[8];
  }
  __syncthreads();
  if (tid < 256){
    int i = rowB + tid;
    f32x4 sv = *(f32x4*)&redS[tid*4];
    f32x4 qv = *(f32x4*)&redS[1024 + tid*4];
    f32x4 mv = *(f32x4*)&redS[2048 + tid*4];
    atomicAdd(rs1+i, sv[0]+sv[1]+sv[2]+sv[3]);
    atomicAdd(rs2+i, qv[0]+qv[1]+qv[2]+qv[3]);
    atomicMinF(rmin+i, fminf(fminf(mv[0],mv[1]), fminf(mv[2],mv[3])));
  }
}

// ---------------- streaming pass 2 (exp) over stored fp16 neg ----------------
__global__ __launch_bounds__(512) void k_p2s(
    const _Float16* __restrict__ neg16, const float* __restrict__ CC, const float* __restrict__ AL,
    const int* __restrict__ pairs, float* __restrict__ rexp, int biOff)
{
  __shared__ float red[1024];
  const int tid = threadIdx.x;
  const int w = tid>>6, lane = tid&63, quad = lane>>4, l16 = lane&15;
  const int wr = w>>2, wc = w&3;
  const int biL = blockIdx.x, bj = blockIdx.y;
  const int bi = biOff + biL;
  const int rowB = bi*256;
  int jcol[4]; bool val[4];
#pragma unroll
  for (int n=0;n<4;n++){
    jcol[n] = bj*256 + wc*64 + n*16 + l16;
    val[n] = jcol[n] < N_NODE;
  }
  size_t tBase = ((size_t)bj*8 + biL)*65536;
#pragma unroll
  for (int m=0;m<8;m++){
    const _Float16* src = neg16 + tBase + ((size_t)(w*8 + m))*1024 + lane*16;
    half8 v0 = *(const half8*)(src);
    half8 v1 = *(const half8*)(src + 8);
    _Float16 h16[16];
    *(half8*)&h16[0] = v0; *(half8*)&h16[8] = v1;
#pragma unroll
    for (int reg=0;reg<4;reg++){
      int il = wr*128 + m*16 + quad*4 + reg;
      int i = rowB + il;
      int p = i & (BATCH-1);
      int li = pairs[2*p], ri = pairs[2*p+1];
      float C = CC[i], A = AL[i];
      float s = 0.f;
#pragma unroll
      for (int n=0;n<4;n++){
        float neg = (float)h16[reg*4+n];
        bool bad = (jcol[n]==li) | (jcol[n]==ri) | (!val[n]);
        s += bad ? 0.f : __expf(fmaf(-A, neg, C));
      }
#pragma unroll
      for (int msk=1; msk<16; msk<<=1) s += __shfl_xor(s, msk, 64);
      if (l16==0) red[il*4 + wc] = s;
    }
  }
  __syncthreads();
  if (tid < 256){
    f32x4 sv = *(f32x4*)&red[tid*4];
    atomicAdd(rexp + rowB + tid, sv[0]+sv[1]+sv[2]+sv[3]);
  }
}

// ---------------- per-row special-column dots ----------------
__global__ __launch_bounds__(256) void k_corr(
    const int* __restrict__ pairs, const __bf16* __restrict__ Ap, const __bf16* __restrict__ Ep,
    const float* __restrict__ asq, const float* __restrict__ esq,
    float* __restrict__ negl, float* __restrict__ negr, int iOff)
{
  int wave = threadIdx.x>>6, lane = threadIdx.x&63;
  int i = iOff + blockIdx.x*4 + wave;
  int p = i & (BATCH-1);
  int li = pairs[2*p], ri = pairs[2*p+1];
  const __bf16* Ar = Ap + (size_t)(i>>7)*TILE_ELEMS;  int ra = i&127;
  const __bf16* E1 = Ep + (size_t)(li>>7)*TILE_ELEMS; int r1 = li&127;
  const __bf16* E2 = Ep + (size_t)(ri>>7)*TILE_ELEMS; int r2 = ri&127;
  float d1=0.f, d2=0.f;
  for (int c=lane; c<96; c+=64){
    int kb = c>>2, q = c&3;
    bf16x8 a  = *(const bf16x8*)(Ar + kb*KBLK_ELEMS + swz_off(ra, q));
    bf16x8 e1 = *(const bf16x8*)(E1 + kb*KBLK_ELEMS + swz_off(r1, q));
    bf16x8 e2 = *(const bf16x8*)(E2 + kb*KBLK_ELEMS + swz_off(r2, q));
#pragma unroll
    for (int e=0;e<8;e++){
      d1 = fmaf((float)a[e], (float)e1[e], d1);
      d2 = fmaf((float)a[e], (float)e2[e], d2);
    }
  }
  d1 = waveSum(d1); d2 = waveSum(d2);
  if (lane==0){
    float av = asq[i];
    negl[i] = av + esq[li] - 2.f*d1;
    negr[i] = av + esq[ri] - 2.f*d2;
  }
}

// ---------------- stats ----------------
__global__ __launch_bounds__(256) void k_stats(
    const float* __restrict__ rs1, const float* __restrict__ rs2, const float* __restrict__ rmin,
    const float* __restrict__ negl, const float* __restrict__ negr,
    const float* __restrict__ asq, const float* __restrict__ pos, const int* __restrict__ pairs,
    float* __restrict__ MM, float* __restrict__ CC, float* __restrict__ AL, float* __restrict__ rexp, int iOff)
{
  int i = iOff + blockIdx.x*256 + threadIdx.x;
  int p = i & (BATCH-1);
  int li = pairs[2*p], ri = pairs[2*p+1];
  float K = pos[p] + GAMMA_C;
  float av = asq[i];
  float S1 = rs1[i] - (float)PADN*av;
  float S2 = rs2[i] - (float)PADN*av*av;
  float nl = negl[i], nr = negr[i];
  float Sx, Sxx, mx;
  const float invN = 1.f/(float)N_NODE;
  if (li != ri){
    Sx  = -(S1 - nl - nr) - 2.f*K;
    Sxx = (S2 - nl*nl - nr*nr) + 2.f*K*K;
    mx  = fmaxf(K - rmin[i], 0.f);
    float mu = K + Sx*invN;
    float m2 = Sx*invN;
    float var = Sxx*invN - m2*m2;
    float sd = sqrtf(fmaxf(var, 1e-30f));
    float M = LAMB_C*(mx-mu)/sd + TAU_C;
    MM[i] = M; CC[i] = LAMB_C*(K-mu)/sd + TAU_C - M; AL[i] = LAMB_C/sd;
    rexp[i] = 2.f*__expf(LAMB_C*(0.f-mu)/sd + TAU_C - M);
  } else {
    float lossm = nl - K;
    float x = lossm - K;
    Sx  = -(S1 - nl) + x;
    Sxx = (S2 - nl*nl) + x*x;
    mx  = fmaxf(K - rmin[i], lossm);
    float mu = K + Sx*invN;
    float m2 = Sx*invN;
    float var = Sxx*invN - m2*m2;
    float sd = sqrtf(fmaxf(var, 1e-30f));
    float M = LAMB_C*(mx-mu)/sd + TAU_C;
    MM[i] = M; CC[i] = LAMB_C*(K-mu)/sd + TAU_C - M; AL[i] = LAMB_C/sd;
    rexp[i] = __expf(LAMB_C*(lossm-mu)/sd + TAU_C - M);
  }
}

__global__ __launch_bounds__(256) void k_final(const float* __restrict__ mm, const float* __restrict__ rexp, float* __restrict__ out){
  __shared__ float red[256];
  float s = 0.f;
  for (int i=threadIdx.x; i<NROWA; i+=256) s += mm[i] + logf(rexp[i]);
  red[threadIdx.x] = s; __syncthreads();
  for (int st=128; st>0; st>>=1){ if (threadIdx.x<st) red[threadIdx.x]+=red[threadIdx.x+st]; __syncthreads(); }
  if (threadIdx.x==0) out[0] = red[0]*(1.f/BATCH);
}

extern "C" void kernel_launch(void* const* d_in, const int* in_sizes, int n_in,
                              void* d_out, int out_size, void* d_ws, size_t ws_size,
                              hipStream_t stream) {
  const int*   pairs   = (const int*)d_in[0];
  const int*   ent_adj = (const int*)d_in[1];
  const int*   rel_adj = (const int*)d_in[2];
  const int*   adj     = (const int*)d_in[3];
  const int*   r_index = (const int*)d_in[4];
  const float* r_val   = (const float*)d_in[5];
  const float* ent_emb = (const float*)d_in[7];
  const float* rel_emb = (const float*)d_in[8];
  const float* attn_e  = (const float*)d_in[9];
  const float* attn_r  = (const float*)d_in[10];

  char* base = (char*)d_ws;
  size_t off = 0;
  auto take = [&](size_t bytes)->char*{
    char* p = base + off;
    off = (off + bytes + 511) & ~(size_t)511;
    return p;
  };
  // persistent GEMM-phase region (~54 MB)
  __bf16* EP    = (__bf16*)take((size_t)NTILE_E*TILE_ELEMS*2);
  __bf16* AP    = (__bf16*)take((size_t)NTILE_A*TILE_ELEMS*2);
  float*  ESQ   = (float*)take((size_t)EPAD*4);
  float*  ASQ   = (float*)take((size_t)NROWA*4);
  float*  POS   = (float*)take((size_t)BATCH*4);
  float*  RS1   = (float*)take((size_t)NROWA*4);
  float*  RS2   = (float*)take((size_t)NROWA*4);
  float*  RMIN  = (float*)take((size_t)NROWA*4);
  float*  NEGL  = (float*)take((size_t)NROWA*4);
  float*  NEGR  = (float*)take((size_t)NROWA*4);
  float*  MM    = (float*)take((size_t)NROWA*4);
  float*  CCv   = (float*)take((size_t)NROWA*4);
  float*  ALv   = (float*)take((size_t)NROWA*4);
  float*  REXP  = (float*)take((size_t)NROWA*4);

  // graph-phase region (dead by GEMM time) — overlapped by NEG16 (123.7 MB per chunk)
  size_t offG = off;
  __bf16* OUTB = (__bf16*)take((size_t)N_NODE*OUTD*2);
  __bf16* TRI  = (__bf16*)take((size_t)N_TRI*DIM*2);
  float*  ATT4 = (float*)take((size_t)4*N_TRI*4);
  int* RP_E  = (int*)take((size_t)(N_NODE+1)*4);
  int* RP_R  = (int*)take((size_t)(N_NODE+1)*4);
  int* RP_A  = (int*)take((size_t)(N_NODE+1)*4);
  int* IDX_E = (int*)take((size_t)N_TRI*4);
  int* IDX_R = (int*)take((size_t)N_TRI*4);
  int* IDX_A = (int*)take((size_t)N_TRI*4);
  int* CNT6  = (int*)take((size_t)6*N_NODE*4);
  int* BTOT  = (int*)take((size_t)3*NBLK_SCAN*4);
  int* CNT_E = CNT6,            *CNT_R = CNT6 + N_NODE,   *CNT_A = CNT6 + 2*N_NODE;
  int* CUR_E = CNT6 + 3*N_NODE, *CUR_R = CNT6 + 4*N_NODE, *CUR_A = CNT6 + 5*N_NODE;

  _Float16* NEG16 = (_Float16*)(base + offG);   // 123.7 MB per chunk

  const int* cols = adj + N_TRI;

  // ---- init ----
  k_fill<<<192,256,0,stream>>>((float*)CNT6, (long)6*N_NODE, 0.f);

  // ---- CSR builds ----
  k_hist<<<782,256,0,stream>>>(ent_adj, CNT_E);
  k_hist<<<782,256,0,stream>>>(rel_adj, CNT_R);
  k_hist<<<782,256,0,stream>>>(adj,     CNT_A);
  dim3 gsA(NBLK_SCAN, 3, 1);
  k_scanA<<<gsA,256,0,stream>>>(CNT_E, CNT_R, CNT_A, RP_E, RP_R, RP_A, BTOT, N_NODE);
  k_scanB<<<3,128,0,stream>>>(BTOT, RP_E, RP_R, RP_A, N_NODE);
  k_scanC<<<gsA,256,0,stream>>>(RP_E, RP_R, RP_A, BTOT, N_NODE);
  k_place<<<782,256,0,stream>>>(ent_adj, ent_adj+N_TRI, RP_E, CUR_E, IDX_E, 1);
  k_place<<<782,256,0,stream>>>(rel_adj, rel_adj+N_TRI, RP_R, CUR_R, IDX_R, 1);
  k_place<<<782,256,0,stream>>>(adj,     (const int*)0, RP_A, CUR_A, IDX_A, 0);

  // ---- feature pipeline ----
  k_feat0<<<7500,256,0,stream>>>(RP_E, IDX_E, RP_R, IDX_R, ent_emb, rel_emb, OUTB);
  k_trinorm<<<25000,256,0,stream>>>(r_index+N_TRI, r_val, rel_emb, TRI, attn_e, attn_r, ATT4);
  k_gat<<<7500,256,0,stream>>>(RP_A, IDX_A, cols, TRI,
                               ATT4 + 0*N_TRI, ATT4 + 2*N_TRI, OUTB, 0, 256);
  k_gat<<<7500,256,0,stream>>>(RP_A, IDX_A, cols, TRI,
                               ATT4 + 1*N_TRI, ATT4 + 3*N_TRI, OUTB, 256, 512);

  // ---- loss prep ----
  k_packE<<<7552,256,0,stream>>>(OUTB, EP, ESQ);
  k_packA<<<512,256,0,stream>>>(pairs, EP, OUTB, ESQ, AP, ASQ, POS);
  k_fill<<<16,256,0,stream>>>(RS1, (long)NROWA, 0.f);
  k_fill<<<16,256,0,stream>>>(RS2, (long)NROWA, 0.f);
  k_fill<<<16,256,0,stream>>>(RMIN,(long)NROWA, 1e30f);

  // ---- loss phase: 2 row-chunks of 8x256 rows; moments fused into GEMM epilogue ----
  for (int ch=0; ch<2; ++ch){
    int biOff = ch*NTILE_AI;     // 256-row tile offset
    int iOff  = ch*2048;
    dim3 gg(NTILE_AI, NTILE_EJ, 1);
    k_gemm<<<gg,512,0,stream>>>(AP, EP, ASQ, ESQ, pairs, RS1, RS2, RMIN, NEG16, biOff);
    k_corr<<<512,256,0,stream>>>(pairs, AP, EP, ASQ, ESQ, NEGL, NEGR, iOff);
    k_stats<<<8,256,0,stream>>>(RS1, RS2, RMIN, NEGL, NEGR, ASQ, POS, pairs,
                                MM, CCv, ALv, REXP, iOff);
    k_p2s<<<gg,512,0,stream>>>(NEG16, CCv, ALv, pairs, REXP, biOff);
  }
  k_final<<<1,256,0,stream>>>(MM, REXP, (float*)d_out);
}

// Round 2
// 706.842 us; speedup vs baseline: 1.0216x; 1.0216x over previous
//
#include <hip/hip_runtime.h>
#include <hip/hip_bf16.h>
#include <math.h>

#define N_NODE 30000
#define N_TRI  200000
#define DIM    128
#define OUTD   768
#define BATCH  2048
#define NROWA  4096
#define EPAD   30208   // 118*256 = 236*128
#define PADN   208     // EPAD - N_NODE
#define NTILE_E 236    // 128-row tiles in Ep
#define NTILE_A 32     // 128-row tiles in Ap
#define NTILE_EJ 118   // 256-col tiles of E
#define NTILE_AI 8     // 256-row tiles per chunk (2048/256)
#define NBLK_SCAN 118  // ceil(30000/256)
#define TILE_ELEMS (128*OUTD)
#define KBLK_ELEMS (128*32)
#define GAMMA_C 3.0f
#define LAMB_C  30.0f
#define TAU_C   10.0f

typedef __attribute__((ext_vector_type(8)))  __bf16 bf16x8;
typedef __attribute__((ext_vector_type(4)))  __bf16 bf16x4;
typedef __attribute__((ext_vector_type(2)))  __bf16 bf16x2;
typedef __attribute__((ext_vector_type(8)))  _Float16 half8;
typedef __attribute__((ext_vector_type(4)))  float f32x4;

__device__ __forceinline__ float waveSum(float v){
#pragma unroll
  for (int m=1;m<64;m<<=1) v += __shfl_xor(v, m, 64);
  return v;
}
__device__ __forceinline__ float halfSum(float v){
#pragma unroll
  for (int m=1;m<32;m<<=1) v += __shfl_xor(v, m, 64);
  return v;
}

__device__ __forceinline__ void atomicMinF(float* a, float v){
  if (v >= 0.f) atomicMin((int*)a, __float_as_int(v));
  else          atomicMax((unsigned int*)a, __float_as_uint(v));
}

__device__ __forceinline__ void gl2lds16(const void* g, void* l){
  __builtin_amdgcn_global_load_lds(
      (const __attribute__((address_space(1))) char*)g,
      (__attribute__((address_space(3))) char*)l, 16, 0, 0);
}

__device__ __forceinline__ int swz_off(int r, int q){
  return r*32 + ((q ^ ((r>>1)&3))<<3);
}

// ---------------- fill ----------------
__global__ void k_fill(float* __restrict__ p, long n, float v){
  long i = (long)blockIdx.x*blockDim.x + threadIdx.x;
  long st = (long)gridDim.x*blockDim.x;
  for (; i<n; i+=st) p[i]=v;
}

// ---------------- CSR build ----------------
__global__ __launch_bounds__(256) void k_hist(const int* __restrict__ rows, int* __restrict__ cnt){
  int t = blockIdx.x*256 + threadIdx.x;
  if (t < N_TRI) atomicAdd(&cnt[rows[t]], 1);
}

__global__ __launch_bounds__(256) void k_scanA(
    const int* __restrict__ c0, const int* __restrict__ c1, const int* __restrict__ c2,
    int* __restrict__ r0, int* __restrict__ r1, int* __restrict__ r2,
    int* __restrict__ btot, int n){
  const int* cnt = blockIdx.y==0 ? c0 : (blockIdx.y==1 ? c1 : c2);
  int* rp        = blockIdx.y==0 ? r0 : (blockIdx.y==1 ? r1 : r2);
  __shared__ int buf[256];
  int i = blockIdx.x*256 + threadIdx.x;
  int v = (i<n) ? cnt[i] : 0;
  buf[threadIdx.x] = v;
  __syncthreads();
  for (int off=1; off<256; off<<=1){
    int t = (threadIdx.x>=off) ? buf[threadIdx.x-off] : 0;
    __syncthreads();
    buf[threadIdx.x] += t;
    __syncthreads();
  }
  if (i<n) rp[i] = buf[threadIdx.x] - v;
  if (threadIdx.x==255) btot[blockIdx.y*NBLK_SCAN + blockIdx.x] = buf[255];
}

__global__ __launch_bounds__(128) void k_scanB(int* __restrict__ btot,
    int* __restrict__ r0, int* __restrict__ r1, int* __restrict__ r2, int n){
  __shared__ int buf[128];
  int c = blockIdx.x;
  int v = (threadIdx.x < NBLK_SCAN) ? btot[c*NBLK_SCAN + threadIdx.x] : 0;
  buf[threadIdx.x] = v;
  __syncthreads();
  for (int off=1; off<128; off<<=1){
    int t = (threadIdx.x>=off) ? buf[threadIdx.x-off] : 0;
    __syncthreads();
    buf[threadIdx.x] += t;
    __syncthreads();
  }
  if (threadIdx.x < NBLK_SCAN) btot[c*NBLK_SCAN + threadIdx.x] = buf[threadIdx.x] - v;
  if (threadIdx.x == 127){
    int* rp = c==0 ? r0 : (c==1 ? r1 : r2);
    rp[n] = buf[127];
  }
}

__global__ __launch_bounds__(256) void k_scanC(
    int* __restrict__ r0, int* __restrict__ r1, int* __restrict__ r2,
    const int* __restrict__ btot, int n){
  int* rp = blockIdx.y==0 ? r0 : (blockIdx.y==1 ? r1 : r2);
  int i = blockIdx.x*256 + threadIdx.x;
  if (i<n) rp[i] += btot[blockIdx.y*NBLK_SCAN + blockIdx.x];
}

__global__ __launch_bounds__(256) void k_place(const int* __restrict__ rows, const int* __restrict__ vals,
                        const int* __restrict__ rowptr, int* __restrict__ cur, int* __restrict__ idx, int mode){
  int t = blockIdx.x*256 + threadIdx.x;
  if (t < N_TRI){
    int r = rows[t];
    int p = atomicAdd(&cur[r], 1);
    idx[rowptr[r] + p] = mode ? vals[t] : t;
  }
}

// ---------------- fused sparse means + tanh -> interleaved bf16 features ----------------
__global__ __launch_bounds__(256) void k_feat0(
    const int* __restrict__ rpE, const int* __restrict__ idxE,
    const int* __restrict__ rpR, const int* __restrict__ idxR,
    const float* __restrict__ ent_emb, const float* __restrict__ rel_emb,
    __bf16* __restrict__ outb){
  int wave = threadIdx.x>>6, lane = threadIdx.x&63;
  int i = blockIdx.x*4 + wave;
  if (i >= N_NODE) return;
  int bE = rpE[i], eE = rpE[i+1];
  int bR = rpR[i], eR = rpR[i+1];
  float2 aE = {0.f,0.f}, aR = {0.f,0.f};
  for (int k=bE; k<eE; ++k){
    int c = idxE[k];
    float2 v = *(const float2*)(ent_emb + (size_t)c*DIM + lane*2);
    aE.x += v.x; aE.y += v.y;
  }
  for (int k=bR; k<eR; ++k){
    int c = idxR[k];
    float2 v = *(const float2*)(rel_emb + (size_t)c*DIM + lane*2);
    aR.x += v.x; aR.y += v.y;
  }
  float ie = 1.f/fmaxf((float)(eE-bE), 1.f);
  float ir = 1.f/fmaxf((float)(eR-bR), 1.f);
  bf16x2 oE, oR;
  oE[0] = (__bf16)tanhf(aE.x*ie); oE[1] = (__bf16)tanhf(aE.y*ie);
  oR[0] = (__bf16)tanhf(aR.x*ir); oR[1] = (__bf16)tanhf(aR.y*ir);
  *(bf16x2*)(outb + (size_t)i*OUTD +   0 + lane*2) = oE;
  *(bf16x2*)(outb + (size_t)i*OUTD + 128 + lane*2) = oR;
}

// ---------------- tri_rel direct + norm(bf16) + att logits ----------------
__global__ __launch_bounds__(256) void k_trinorm(
    const int* __restrict__ ridx1, const float* __restrict__ rval,
    const float* __restrict__ rel_emb,
    __bf16* __restrict__ tri, const float* __restrict__ attnE,
    const float* __restrict__ attnR, float* __restrict__ att4){
  __shared__ float ak[4][DIM];
  int tid = threadIdx.x;
  for (int idx=tid; idx<4*DIM; idx+=256){
    int k = idx>>7, d = idx&127;
    ak[k][d] = (k<2) ? attnE[k*DIM + d] : attnR[(k-2)*DIM + d];
  }
  __syncthreads();
  int half = tid>>5, l31 = tid&31;
  int t = blockIdx.x*8 + half;
  if (t >= N_TRI) return;
  int rr = ridx1[t];
  float rv = rval[t];
  float4 v = *(const float4*)(rel_emb + (size_t)rr*DIM + l31*4);
  v.x *= rv; v.y *= rv; v.z *= rv; v.w *= rv;
  float ss = halfSum(v.x*v.x + v.y*v.y + v.z*v.z + v.w*v.w);
  float inv = 1.f/fmaxf(sqrtf(ss), 1e-12f);
  v.x *= inv; v.y *= inv; v.z *= inv; v.w *= inv;
  bf16x4 b; b[0]=(__bf16)v.x; b[1]=(__bf16)v.y; b[2]=(__bf16)v.z; b[3]=(__bf16)v.w;
  *(bf16x4*)(tri + (size_t)t*DIM + l31*4) = b;
#pragma unroll
  for (int k=0;k<4;k++){
    const float* a = &ak[k][l31*4];
    float p = halfSum(v.x*a[0] + v.y*a[1] + v.z*a[2] + v.w*a[3]);
    if (l31==0) att4[(size_t)k*N_TRI + t] = p;
  }
}

// ---------------- fused GAT layer ----------------
__global__ __launch_bounds__(256) void k_gat(
    const int* __restrict__ rowptr, const int* __restrict__ idx, const int* __restrict__ cols,
    const __bf16* __restrict__ tri,
    const float* __restrict__ attE, const float* __restrict__ attR,
    __bf16* __restrict__ outb, int inOff, int outOff){
  int wave = threadIdx.x>>6, lane = threadIdx.x&63;
  int i = blockIdx.x*4 + wave;
  if (i >= N_NODE) return;
  int l31 = lane&31;
  const float* att = (lane < 32) ? attE : attR;
  int beg = rowptr[i], end = rowptr[i+1];
  float a0=0.f, a1=0.f, a2=0.f, a3=0.f;
  if (end > beg){
    float z = 0.f;
    int t0 = idx[beg];
    int c0 = cols[t0];
    bf16x4 u4 = *(const bf16x4*)(tri + (size_t)t0*DIM + l31*4);
    bf16x4 f4 = *(const bf16x4*)(outb + (size_t)c0*OUTD + inOff + lane*4);
    float atv = att[t0];
    for (int k=beg; k<end; ++k){
      bf16x4 u4c = u4, f4c = f4;
      float atc = atv;
      if (k+1 < end){
        int t1 = idx[k+1];
        int c1 = cols[t1];
        u4 = *(const bf16x4*)(tri + (size_t)t1*DIM + l31*4);
        f4 = *(const bf16x4*)(outb + (size_t)c1*OUTD + inOff + lane*4);
        atv = att[t1];
      }
      float u0=(float)u4c[0], u1=(float)u4c[1], u2=(float)u4c[2], u3=(float)u4c[3];
      float f0=(float)f4c[0], f1=(float)f4c[1], f2=(float)f4c[2], f3=(float)f4c[3];
      float d = f0*u0 + f1*u1 + f2*u2 + f3*u3;
#pragma unroll
      for (int mm=1; mm<32; mm<<=1) d += __shfl_xor(d, mm, 64);
      float w = __expf(atc);
      z += w;
      float d2 = 2.f*d;
      a0 = fmaf(w, fmaf(-d2, u0, f0), a0);
      a1 = fmaf(w, fmaf(-d2, u1, f1), a1);
      a2 = fmaf(w, fmaf(-d2, u2, f2), a2);
      a3 = fmaf(w, fmaf(-d2, u3, f3), a3);
    }
    float iz = 1.f/z;
    a0 *= iz; a1 *= iz; a2 *= iz; a3 *= iz;
  }
  bf16x4 o;
  o[0] = (__bf16)tanhf(a0); o[1] = (__bf16)tanhf(a1);
  o[2] = (__bf16)tanhf(a2); o[3] = (__bf16)tanhf(a3);
  *(bf16x4*)(outb + (size_t)i*OUTD + outOff + lane*4) = o;
}

// ---------------- pack E ----------------
__global__ __launch_bounds__(256) void k_packE(const __bf16* __restrict__ outb, __bf16* __restrict__ Ep, float* __restrict__ esq){
  const int perm[6] = {0,2,4,1,3,5};
  int wave = threadIdx.x>>6, lane = threadIdx.x&63;
  int j = blockIdx.x*4 + wave;
  if (j >= EPAD) return;
  int jt = j>>7, r = j&127;
  __bf16* tb = Ep + (size_t)jt*TILE_ELEMS;
  float ss = 0.f;
  for (int c=lane; c<96; c+=64){
    int kb = c>>2, q = c&3;
    bf16x8 o;
    if (j < N_NODE){
      int ib = perm[c>>4], wb = c&15;
      o = *(const bf16x8*)(outb + (size_t)j*OUTD + ib*128 + wb*8);
#pragma unroll
      for (int e=0;e<8;e++){ float v = (float)o[e]; ss += v*v; }
    } else {
#pragma unroll
      for (int e=0;e<8;e++) o[e] = (__bf16)0.f;
    }
    *(bf16x8*)(tb + kb*KBLK_ELEMS + swz_off(r, q)) = o;
  }
  ss = waveSum(ss);
  if (lane==0) esq[j] = (j < N_NODE) ? ss : 0.f;
}

__global__ __launch_bounds__(256) void k_packA(const int* __restrict__ pairs, const __bf16* __restrict__ Ep,
    const __bf16* __restrict__ outb, const float* __restrict__ esq,
    __bf16* __restrict__ Ap, float* __restrict__ asq, float* __restrict__ pos){
  int wave = threadIdx.x>>6, lane = threadIdx.x&63;
  int p = blockIdx.x*4 + wave;
  if (p >= BATCH) return;
  int l = pairs[2*p], r = pairs[2*p+1];
  float ss = 0.f;
#pragma unroll
  for (int c=0;c<6;c++){
    int d = c*128 + lane*2;
    bf16x2 a = *(const bf16x2*)(outb + (size_t)l*OUTD + d);
    bf16x2 b = *(const bf16x2*)(outb + (size_t)r*OUTD + d);
    float dx = (float)a[0]-(float)b[0], dy = (float)a[1]-(float)b[1];
    ss += dx*dx + dy*dy;
  }
  ss = waveSum(ss);
  if (lane==0){ pos[p] = ss; asq[p] = esq[l]; asq[p+BATCH] = esq[r]; }
  int lt = l>>7, lr = l&127;
  int rt2 = r>>7, rr = r&127;
  int p0t = p>>7, p0r = p&127;
  int p1t = (p+BATCH)>>7, p1r = (p+BATCH)&127;
  for (int c=lane; c<96; c+=64){
    int kb = c>>2, q = c&3;
    bf16x8 vl = *(const bf16x8*)(Ep + (size_t)lt*TILE_ELEMS + kb*KBLK_ELEMS + swz_off(lr, q));
    *(bf16x8*)(Ap + (size_t)p0t*TILE_ELEMS + kb*KBLK_ELEMS + swz_off(p0r, q)) = vl;
    bf16x8 vr = *(const bf16x8*)(Ep + (size_t)rt2*TILE_ELEMS + kb*KBLK_ELEMS + swz_off(rr, q));
    *(bf16x8*)(Ap + (size_t)p1t*TILE_ELEMS + kb*KBLK_ELEMS + swz_off(p1r, q)) = vr;
  }
}

// ---------------- GEMM: 256x256 tile, 8 waves, derived-waits 4-phase pipeline ----------------
// LDS: 4 DISTINCT objects (A0,A1,B0,B1; 32 KB each) so the waitcnt pass can prove
// cross-buffer ds_read/DMA no-alias, + __builtin_amdgcn_s_waitcnt (not asm) so the
// pass's scoreboard KNOWS which LDS-DMAs our counted vmcnt drained -> no forced
// vmcnt(0) drains before the per-phase ds_reads (R1's failure mode).
// Schedule per tile t: ph1{dsA lo + dsB lo | stage A(t+1)h0} ph2{dsB hi | stage A(t+1)h1}
// ph3{dsA hi | stage B(t+2)h0 -> CURB obj} ph4{stage B(t+2)h1 ; vmcnt(4)}.
// Steady state after the per-tile vmcnt(4): exactly B(t+2) (4 ops) in flight.

#define LOADS_A(CA, mbase) \
  _Pragma("unroll") \
  for (int m4_=0;m4_<4;m4_++){ \
    aF[m4_][0] = *(const bf16x8*)((const char*)(CA) + aOff + ((mbase)+m4_)*1024); \
    aF[m4_][1] = *(const bf16x8*)((const char*)(CA) + aOff + 8192 + ((mbase)+m4_)*1024); \
  }

#define LOADS_B(CB, bsel) \
  _Pragma("unroll") \
  for (int n2_=0;n2_<2;n2_++){ \
    bF[bsel][n2_][0] = *(const bf16x8*)((const char*)(CB) + bOff + ((bsel)*2+n2_)*1024); \
    bF[bsel][n2_][1] = *(const bf16x8*)((const char*)(CB) + bOff + 8192 + ((bsel)*2+n2_)*1024); \
  }

#define MFMA_Q(h, b) \
  _Pragma("unroll") \
  for (int m4_=0;m4_<4;m4_++) \
    _Pragma("unroll") \
    for (int n2_=0;n2_<2;n2_++){ \
      acc[(h)*4+m4_][(b)*2+n2_] = __builtin_amdgcn_mfma_f32_16x16x32_bf16(aF[m4_][0], bF[b][n2_][0], acc[(h)*4+m4_][(b)*2+n2_],0,0,0); \
      acc[(h)*4+m4_][(b)*2+n2_] = __builtin_amdgcn_mfma_f32_16x16x32_bf16(aF[m4_][1], bF[b][n2_][1], acc[(h)*4+m4_][(b)*2+n2_],0,0,0); \
    }

#define STAGE_A(OBJ, t, rt) { \
  const __bf16* s_ = Abase + (size_t)(rt)*TILE_ELEMS + (size_t)((t)*2)*KBLK_ELEMS + tid*8; \
  char* d_ = (char*)(OBJ) + (rt)*16384 + tid*16; \
  gl2lds16(s_, d_); gl2lds16(s_ + KBLK_ELEMS, d_ + 8192); }

#define STAGE_B(OBJ, t, rt) { \
  const __bf16* s_ = Bbase + (size_t)(rt)*TILE_ELEMS + (size_t)((t)*2)*KBLK_ELEMS + tid*8; \
  char* d_ = (char*)(OBJ) + (rt)*16384 + tid*16; \
  gl2lds16(s_, d_); gl2lds16(s_ + KBLK_ELEMS, d_ + 8192); }

// s_waitcnt imm (gfx9 encoding): vmcnt[3:0]|exp<<4|lgkm<<8|vmcnt_hi<<14
#define WAIT_VM4 __builtin_amdgcn_s_waitcnt(0xF74)
#define WAIT_VM0 __builtin_amdgcn_s_waitcnt(0xF70)

#define TILE_BODY(CA, CB, SA0, SA1, SB0, SB1, WAITC) { \
  LOADS_A(CA, 0); \
  LOADS_B(CB, 0); \
  SA0; \
  __builtin_amdgcn_s_barrier(); \
  __builtin_amdgcn_s_setprio(1); MFMA_Q(0,0); __builtin_amdgcn_s_setprio(0); \
  __builtin_amdgcn_s_barrier(); \
  LOADS_B(CB, 1); \
  SA1; \
  __builtin_amdgcn_s_barrier(); \
  __builtin_amdgcn_s_setprio(1); MFMA_Q(0,1); __builtin_amdgcn_s_setprio(0); \
  __builtin_amdgcn_s_barrier(); \
  LOADS_A(CA, 4); \
  SB0; \
  __builtin_amdgcn_s_barrier(); \
  __builtin_amdgcn_s_setprio(1); MFMA_Q(1,0); __builtin_amdgcn_s_setprio(0); \
  __builtin_amdgcn_s_barrier(); \
  SB1; \
  __builtin_amdgcn_s_setprio(1); MFMA_Q(1,1); __builtin_amdgcn_s_setprio(0); \
  WAITC; \
  __builtin_amdgcn_s_barrier(); }

__global__ __launch_bounds__(512,2) void k_gemm(
    const __bf16* __restrict__ Ap, const __bf16* __restrict__ Ep,
    const float* __restrict__ asq, const float* __restrict__ esq,
    const int* __restrict__ pairs,
    float* __restrict__ rs1, float* __restrict__ rs2, float* __restrict__ rmin,
    _Float16* __restrict__ neg16, int biOff)
{
  __shared__ __align__(16) __bf16 sA0[16384];
  __shared__ __align__(16) __bf16 sA1[16384];
  __shared__ __align__(16) __bf16 sB0[16384];
  __shared__ __align__(16) __bf16 sB1[16384];
  const int tid = threadIdx.x;
  const int w = tid>>6, lane = tid&63, quad = lane>>4, l16 = lane&15;
  const int wr = w>>2, wc = w&3;

  // XCD-aware swizzle (944 blocks, 944%8==0 -> bijective): blocks on one XCD
  // share bj runs and the full biL set -> A panel + active B tile L2-resident.
  int wg = blockIdx.x*NTILE_EJ + blockIdx.y;
  const int biL = wg & 7;
  const int bj  = wg >> 3;
  const int bi  = biOff + biL;

  const __bf16* Abase = Ap + (size_t)(bi*2)*TILE_ELEMS;
  const __bf16* Bbase = Ep + (size_t)(bj*2)*TILE_ELEMS;

  const int s0b = swz_off(l16, quad)*2;          // byte offset within a 128x32 chunk
  const int aOff = wr*16384 + s0b;               // + ks*8192 + m*1024
  const int bOff = (wc>>1)*16384 + (wc&1)*4096 + s0b;

  const f32x4 zf = {0.f,0.f,0.f,0.f};
  f32x4 acc[8][4];
#pragma unroll
  for (int m=0;m<8;m++)
#pragma unroll
    for (int n=0;n<4;n++) acc[m][n] = zf;

  bf16x8 aF[4][2], bF[2][2][2];

  // prologue: tile0 (B0,A0) + tile1 B-pair; vmcnt(4) drains tile0, leaves B1 in flight
  STAGE_B(sB0, 0, 0); STAGE_B(sB0, 0, 1);
  STAGE_A(sA0, 0, 0); STAGE_A(sA0, 0, 1);
  STAGE_B(sB1, 1, 0); STAGE_B(sB1, 1, 1);
  WAIT_VM4;
  __builtin_amdgcn_s_barrier();

#pragma unroll 1
  for (int t2=0; t2<5; ++t2){
    const int te = 2*t2;
    TILE_BODY(sA0, sB0,
              STAGE_A(sA1, te+1, 0), STAGE_A(sA1, te+1, 1),
              STAGE_B(sB0, te+2, 0), STAGE_B(sB0, te+2, 1),
              WAIT_VM4);
    TILE_BODY(sA1, sB1,
              STAGE_A(sA0, te+2, 0), STAGE_A(sA0, te+2, 1),
              STAGE_B(sB1, te+3, 0), STAGE_B(sB1, te+3, 1),
              WAIT_VM4);
  }
  // tile 10: stage A(11) only; drain everything for the final tile
  TILE_BODY(sA0, sB0,
            STAGE_A(sA1, 11, 0), STAGE_A(sA1, 11, 1),
            (void)0, (void)0,
            WAIT_VM0);
  // tile 11: pure compute
  TILE_BODY(sA1, sB1, (void)0, (void)0, (void)0, (void)0, (void)0);

  // ---- epilogue: neg16 store + quad-reduced moment partials (scratch over sA0) ----
  float* redS = (float*)sA0;   // [3][256][4] fp32 = 12KB
  int jcol[4]; bool val[4]; float esqv[4];
#pragma unroll
  for (int n=0;n<4;n++){
    jcol[n] = bj*256 + wc*64 + n*16 + l16;
    val[n] = jcol[n] < N_NODE;
    esqv[n] = esq[jcol[n]];
  }
  const int rowB = bi*256;
  size_t tBase = ((size_t)bj*8 + biL)*65536;
#pragma unroll
  for (int m=0;m<8;m++){
    _Float16 h16[16];
#pragma unroll
    for (int reg=0;reg<4;reg++){
      int il = wr*128 + m*16 + quad*4 + reg;
      int i = rowB + il;
      int p = i & (BATCH-1);
      int li = pairs[2*p], ri = pairs[2*p+1];
      float av = asq[i];
      float s=0.f, q=0.f, mn=1e30f;
#pragma unroll
      for (int n=0;n<4;n++){
        float neg = (av + esqv[n]) - 2.f*acc[m][n][reg];
        s += neg;
        q = fmaf(neg, neg, q);
        bool bad = (jcol[n]==li) | (jcol[n]==ri) | (!val[n]);
        mn = fminf(mn, bad ? 1e30f : neg);
        h16[reg*4+n] = (_Float16)neg;
      }
#pragma unroll
      for (int msk=1; msk<16; msk<<=1){
        s += __shfl_xor(s, msk, 64);
        q += __shfl_xor(q, msk, 64);
        mn = fminf(mn, __shfl_xor(mn, msk, 64));
      }
      if (l16==0){
        redS[       il*4 + wc] = s;
        redS[1024 + il*4 + wc] = q;
        redS[2048 + il*4 + wc] = mn;
      }
    }
    _Float16* dst = neg16 + tBase + ((size_t)(w*8 + m))*1024 + lane*16;
    *(half8*)(dst)     = *(half8*)&h16[0];
    *(half8*)(dst + 8) = *(half8*)&h16[8];
  }
  __syncthreads();
  if (tid < 256){
    int i = rowB + tid;
    f32x4 sv = *(f32x4*)&redS[tid*4];
    f32x4 qv = *(f32x4*)&redS[1024 + tid*4];
    f32x4 mv = *(f32x4*)&redS[2048 + tid*4];
    atomicAdd(rs1+i, sv[0]+sv[1]+sv[2]+sv[3]);
    atomicAdd(rs2+i, qv[0]+qv[1]+qv[2]+qv[3]);
    atomicMinF(rmin+i, fminf(fminf(mv[0],mv[1]), fminf(mv[2],mv[3])));
  }
}

// ---------------- streaming pass 2 (exp) over stored fp16 neg ----------------
__global__ __launch_bounds__(512) void k_p2s(
    const _Float16* __restrict__ neg16, const float* __restrict__ CC, const float* __restrict__ AL,
    const int* __restrict__ pairs, float* __restrict__ rexp, int biOff)
{
  __shared__ float red[1024];
  const int tid = threadIdx.x;
  const int w = tid>>6, lane = tid&63, quad = lane>>4, l16 = lane&15;
  const int wr = w>>2, wc = w&3;
  const int biL = blockIdx.x, bj = blockIdx.y;
  const int bi = biOff + biL;
  const int rowB = bi*256;
  int jcol[4]; bool val[4];
#pragma unroll
  for (int n=0;n<4;n++){
    jcol[n] = bj*256 + wc*64 + n*16 + l16;
    val[n] = jcol[n] < N_NODE;
  }
  size_t tBase = ((size_t)bj*8 + biL)*65536;
#pragma unroll
  for (int m=0;m<8;m++){
    const _Float16* src = neg16 + tBase + ((size_t)(w*8 + m))*1024 + lane*16;
    half8 v0 = *(const half8*)(src);
    half8 v1 = *(const half8*)(src + 8);
    _Float16 h16[16];
    *(half8*)&h16[0] = v0; *(half8*)&h16[8] = v1;
#pragma unroll
    for (int reg=0;reg<4;reg++){
      int il = wr*128 + m*16 + quad*4 + reg;
      int i = rowB + il;
      int p = i & (BATCH-1);
      int li = pairs[2*p], ri = pairs[2*p+1];
      float C = CC[i], A = AL[i];
      float s = 0.f;
#pragma unroll
      for (int n=0;n<4;n++){
        float neg = (float)h16[reg*4+n];
        bool bad = (jcol[n]==li) | (jcol[n]==ri) | (!val[n]);
        s += bad ? 0.f : __expf(fmaf(-A, neg, C));
      }
#pragma unroll
      for (int msk=1; msk<16; msk<<=1) s += __shfl_xor(s, msk, 64);
      if (l16==0) red[il*4 + wc] = s;
    }
  }
  __syncthreads();
  if (tid < 256){
    f32x4 sv = *(f32x4*)&red[tid*4];
    atomicAdd(rexp + rowB + tid, sv[0]+sv[1]+sv[2]+sv[3]);
  }
}

// ---------------- per-row special-column dots ----------------
__global__ __launch_bounds__(256) void k_corr(
    const int* __restrict__ pairs, const __bf16* __restrict__ Ap, const __bf16* __restrict__ Ep,
    const float* __restrict__ asq, const float* __restrict__ esq,
    float* __restrict__ negl, float* __restrict__ negr, int iOff)
{
  int wave = threadIdx.x>>6, lane = threadIdx.x&63;
  int i = iOff + blockIdx.x*4 + wave;
  int p = i & (BATCH-1);
  int li = pairs[2*p], ri = pairs[2*p+1];
  const __bf16* Ar = Ap + (size_t)(i>>7)*TILE_ELEMS;  int ra = i&127;
  const __bf16* E1 = Ep + (size_t)(li>>7)*TILE_ELEMS; int r1 = li&127;
  const __bf16* E2 = Ep + (size_t)(ri>>7)*TILE_ELEMS; int r2 = ri&127;
  float d1=0.f, d2=0.f;
  for (int c=lane; c<96; c+=64){
    int kb = c>>2, q = c&3;
    bf16x8 a  = *(const bf16x8*)(Ar + kb*KBLK_ELEMS + swz_off(ra, q));
    bf16x8 e1 = *(const bf16x8*)(E1 + kb*KBLK_ELEMS + swz_off(r1, q));
    bf16x8 e2 = *(const bf16x8*)(E2 + kb*KBLK_ELEMS + swz_off(r2, q));
#pragma unroll
    for (int e=0;e<8;e++){
      d1 = fmaf((float)a[e], (float)e1[e], d1);
      d2 = fmaf((float)a[e], (float)e2[e], d2);
    }
  }
  d1 = waveSum(d1); d2 = waveSum(d2);
  if (lane==0){
    float av = asq[i];
    negl[i] = av + esq[li] - 2.f*d1;
    negr[i] = av + esq[ri] - 2.f*d2;
  }
}

// ---------------- stats ----------------
__global__ __launch_bounds__(256) void k_stats(
    const float* __restrict__ rs1, const float* __restrict__ rs2, const float* __restrict__ rmin,
    const float* __restrict__ negl, const float* __restrict__ negr,
    const float* __restrict__ asq, const float* __restrict__ pos, const int* __restrict__ pairs,
    float* __restrict__ MM, float* __restrict__ CC, float* __restrict__ AL, float* __restrict__ rexp, int iOff)
{
  int i = iOff + blockIdx.x*256 + threadIdx.x;
  int p = i & (BATCH-1);
  int li = pairs[2*p], ri = pairs[2*p+1];
  float K = pos[p] + GAMMA_C;
  float av = asq[i];
  float S1 = rs1[i] - (float)PADN*av;
  float S2 = rs2[i] - (float)PADN*av*av;
  float nl = negl[i], nr = negr[i];
  float Sx, Sxx, mx;
  const float invN = 1.f/(float)N_NODE;
  if (li != ri){
    Sx  = -(S1 - nl - nr) - 2.f*K;
    Sxx = (S2 - nl*nl - nr*nr) + 2.f*K*K;
    mx  = fmaxf(K - rmin[i], 0.f);
    float mu = K + Sx*invN;
    float m2 = Sx*invN;
    float var = Sxx*invN - m2*m2;
    float sd = sqrtf(fmaxf(var, 1e-30f));
    float M = LAMB_C*(mx-mu)/sd + TAU_C;
    MM[i] = M; CC[i] = LAMB_C*(K-mu)/sd + TAU_C - M; AL[i] = LAMB_C/sd;
    rexp[i] = 2.f*__expf(LAMB_C*(0.f-mu)/sd + TAU_C - M);
  } else {
    float lossm = nl - K;
    float x = lossm - K;
    Sx  = -(S1 - nl) + x;
    Sxx = (S2 - nl*nl) + x*x;
    mx  = fmaxf(K - rmin[i], lossm);
    float mu = K + Sx*invN;
    float m2 = Sx*invN;
    float var = Sxx*invN - m2*m2;
    float sd = sqrtf(fmaxf(var, 1e-30f));
    float M = LAMB_C*(mx-mu)/sd + TAU_C;
    MM[i] = M; CC[i] = LAMB_C*(K-mu)/sd + TAU_C - M; AL[i] = LAMB_C/sd;
    rexp[i] = __expf(LAMB_C*(lossm-mu)/sd + TAU_C - M);
  }
}

__global__ __launch_bounds__(256) void k_final(const float* __restrict__ mm, const float* __restrict__ rexp, float* __restrict__ out){
  __shared__ float red[256];
  float s = 0.f;
  for (int i=threadIdx.x; i<NROWA; i+=256) s += mm[i] + logf(rexp[i]);
  red[threadIdx.x] = s; __syncthreads();
  for (int st=128; st>0; st>>=1){ if (threadIdx.x<st) red[threadIdx.x]+=red[threadIdx.x+st]; __syncthreads(); }
  if (threadIdx.x==0) out[0] = red[0]*(1.f/BATCH);
}

extern "C" void kernel_launch(void* const* d_in, const int* in_sizes, int n_in,
                              void* d_out, int out_size, void* d_ws, size_t ws_size,
                              hipStream_t stream) {
  const int*   pairs   = (const int*)d_in[0];
  const int*   ent_adj = (const int*)d_in[1];
  const int*   rel_adj = (const int*)d_in[2];
  const int*   adj     = (const int*)d_in[3];
  const int*   r_index = (const int*)d_in[4];
  const float* r_val   = (const float*)d_in[5];
  const float* ent_emb = (const float*)d_in[7];
  const float* rel_emb = (const float*)d_in[8];
  const float* attn_e  = (const float*)d_in[9];
  const float* attn_r  = (const float*)d_in[10];

  char* base = (char*)d_ws;
  size_t off = 0;
  auto take = [&](size_t bytes)->char*{
    char* p = base + off;
    off = (off + bytes + 511) & ~(size_t)511;
    return p;
  };
  // persistent GEMM-phase region (~54 MB)
  __bf16* EP    = (__bf16*)take((size_t)NTILE_E*TILE_ELEMS*2);
  __bf16* AP    = (__bf16*)take((size_t)NTILE_A*TILE_ELEMS*2);
  float*  ESQ   = (float*)take((size_t)EPAD*4);
  float*  ASQ   = (float*)take((size_t)NROWA*4);
  float*  POS   = (float*)take((size_t)BATCH*4);
  float*  RS1   = (float*)take((size_t)NROWA*4);
  float*  RS2   = (float*)take((size_t)NROWA*4);
  float*  RMIN  = (float*)take((size_t)NROWA*4);
  float*  NEGL  = (float*)take((size_t)NROWA*4);
  float*  NEGR  = (float*)take((size_t)NROWA*4);
  float*  MM    = (float*)take((size_t)NROWA*4);
  float*  CCv   = (float*)take((size_t)NROWA*4);
  float*  ALv   = (float*)take((size_t)NROWA*4);
  float*  REXP  = (float*)take((size_t)NROWA*4);

  // graph-phase region (dead by GEMM time) — overlapped by NEG16 (123.7 MB per chunk)
  size_t offG = off;
  __bf16* OUTB = (__bf16*)take((size_t)N_NODE*OUTD*2);
  __bf16* TRI  = (__bf16*)take((size_t)N_TRI*DIM*2);
  float*  ATT4 = (float*)take((size_t)4*N_TRI*4);
  int* RP_E  = (int*)take((size_t)(N_NODE+1)*4);
  int* RP_R  = (int*)take((size_t)(N_NODE+1)*4);
  int* RP_A  = (int*)take((size_t)(N_NODE+1)*4);
  int* IDX_E = (int*)take((size_t)N_TRI*4);
  int* IDX_R = (int*)take((size_t)N_TRI*4);
  int* IDX_A = (int*)take((size_t)N_TRI*4);
  int* CNT6  = (int*)take((size_t)6*N_NODE*4);
  int* BTOT  = (int*)take((size_t)3*NBLK_SCAN*4);
  int* CNT_E = CNT6,            *CNT_R = CNT6 + N_NODE,   *CNT_A = CNT6 + 2*N_NODE;
  int* CUR_E = CNT6 + 3*N_NODE, *CUR_R = CNT6 + 4*N_NODE, *CUR_A = CNT6 + 5*N_NODE;

  _Float16* NEG16 = (_Float16*)(base + offG);   // 123.7 MB per chunk

  const int* cols = adj + N_TRI;

  // ---- init ----
  k_fill<<<192,256,0,stream>>>((float*)CNT6, (long)6*N_NODE, 0.f);

  // ---- CSR builds ----
  k_hist<<<782,256,0,stream>>>(ent_adj, CNT_E);
  k_hist<<<782,256,0,stream>>>(rel_adj, CNT_R);
  k_hist<<<782,256,0,stream>>>(adj,     CNT_A);
  dim3 gsA(NBLK_SCAN, 3, 1);
  k_scanA<<<gsA,256,0,stream>>>(CNT_E, CNT_R, CNT_A, RP_E, RP_R, RP_A, BTOT, N_NODE);
  k_scanB<<<3,128,0,stream>>>(BTOT, RP_E, RP_R, RP_A, N_NODE);
  k_scanC<<<gsA,256,0,stream>>>(RP_E, RP_R, RP_A, BTOT, N_NODE);
  k_place<<<782,256,0,stream>>>(ent_adj, ent_adj+N_TRI, RP_E, CUR_E, IDX_E, 1);
  k_place<<<782,256,0,stream>>>(rel_adj, rel_adj+N_TRI, RP_R, CUR_R, IDX_R, 1);
  k_place<<<782,256,0,stream>>>(adj,     (const int*)0, RP_A, CUR_A, IDX_A, 0);

  // ---- feature pipeline ----
  k_feat0<<<7500,256,0,stream>>>(RP_E, IDX_E, RP_R, IDX_R, ent_emb, rel_emb, OUTB);
  k_trinorm<<<25000,256,0,stream>>>(r_index+N_TRI, r_val, rel_emb, TRI, attn_e, attn_r, ATT4);
  k_gat<<<7500,256,0,stream>>>(RP_A, IDX_A, cols, TRI,
                               ATT4 + 0*N_TRI, ATT4 + 2*N_TRI, OUTB, 0, 256);
  k_gat<<<7500,256,0,stream>>>(RP_A, IDX_A, cols, TRI,
                               ATT4 + 1*N_TRI, ATT4 + 3*N_TRI, OUTB, 256, 512);

  // ---- loss prep ----
  k_packE<<<7552,256,0,stream>>>(OUTB, EP, ESQ);
  k_packA<<<512,256,0,stream>>>(pairs, EP, OUTB, ESQ, AP, ASQ, POS);
  k_fill<<<16,256,0,stream>>>(RS1, (long)NROWA, 0.f);
  k_fill<<<16,256,0,stream>>>(RS2, (long)NROWA, 0.f);
  k_fill<<<16,256,0,stream>>>(RMIN,(long)NROWA, 1e30f);

  // ---- loss phase: 2 row-chunks of 8x256 rows; moments fused into GEMM epilogue ----
  for (int ch=0; ch<2; ++ch){
    int biOff = ch*NTILE_AI;     // 256-row tile offset
    int iOff  = ch*2048;
    dim3 gg(NTILE_AI, NTILE_EJ, 1);
    k_gemm<<<gg,512,0,stream>>>(AP, EP, ASQ, ESQ, pairs, RS1, RS2, RMIN, NEG16, biOff);
    k_corr<<<512,256,0,stream>>>(pairs, AP, EP, ASQ, ESQ, NEGL, NEGR, iOff);
    k_stats<<<8,256,0,stream>>>(RS1, RS2, RMIN, NEGL, NEGR, ASQ, POS, pairs,
                                MM, CCv, ALv, REXP, iOff);
    k_p2s<<<gg,512,0,stream>>>(NEG16, CCv, ALv, pairs, REXP, biOff);
  }
  k_final<<<1,256,0,stream>>>(MM, REXP, (float*)d_out);
}